// Round 1
// baseline (261.416 us; speedup 1.0000x reference)
//
#include <hip/hip_runtime.h>

#define B_ 32
#define H_ 56
#define W_ 56
#define CI 128
#define CO 256

#define M_DIM (B_*H_*W_)       // 100352
#define K_DIM (9*CI)           // 1152

#define BM 128
#define BN 128
#define BK 32
#define LDPAD 40               // padded LDS row length in elems (+8 -> 2-way bank aliasing, free)
#define KTILES (K_DIM/BK)      // 36

typedef float          floatx4  __attribute__((ext_vector_type(4)));
typedef unsigned short ushortx4 __attribute__((ext_vector_type(4)));
typedef unsigned short ushortx8 __attribute__((ext_vector_type(8)));
typedef __bf16         bf16x8   __attribute__((ext_vector_type(8)));

__device__ __forceinline__ unsigned short bf16_rne(float f) {
    unsigned u = __builtin_bit_cast(unsigned, f);
    u += 0x7FFFu + ((u >> 16) & 1u);
    return (unsigned short)(u >> 16);
}

// Pre-transpose weights: w[k][n] fp32 (k = (kh*3+kw)*128+c) -> wt[n][k] bf16.
__global__ void wt_transpose_kernel(const float* __restrict__ w,
                                    unsigned short* __restrict__ wt) {
    int t = blockIdx.x * 256 + threadIdx.x;   // 0 .. K_DIM*CO
    int k = t % K_DIM;
    int n = t / K_DIM;
    wt[t] = bf16_rne(w[k * CO + n]);
}

__global__ __launch_bounds__(256, 2)
void conv_gemm_kernel(const float* __restrict__ x,
                      const unsigned short* __restrict__ wt,
                      const float* __restrict__ bias,
                      float* __restrict__ out) {
    __shared__ unsigned short As[BM * LDPAD];
    __shared__ unsigned short Bs[BN * LDPAD];

    const int tid = threadIdx.x;
    const int bx  = blockIdx.x;          // n tile: 0..1
    const int by  = blockIdx.y;          // m tile: 0..783

    // ---- A staging thread mapping: 2 threads per 32-float row ----
    const int m_local = tid >> 1;        // 0..127
    const int halfsel = tid & 1;         // which 16-float half
    const int m  = by * BM + m_local;
    const int wq = m % 56;
    const int hq = (m / 56) % 56;
    const int bq = m / 3136;
    const float* xpix = x + (size_t)((bq * 56 + hq) * 56 + wq) * CI;

    // ---- wave / fragment mapping ----
    const int wid  = tid >> 6;
    const int lane = tid & 63;
    const int lrow = lane & 15;
    const int quad = lane >> 4;
    const int wm   = (wid & 1) * 64;
    const int wn   = (wid >> 1) * 64;

    floatx4 acc[4][4] = {};
    const floatx4 fzero = {0.f, 0.f, 0.f, 0.f};

    for (int kb = 0; kb < KTILES; ++kb) {
        const int kk = kb * BK;
        const int p  = kk >> 7;          // patch index 0..8 (32 | 128 so one patch per K-tile)
        const int kh = p / 3;
        const int kw = p % 3;
        const int c0 = kk & 127;

        // ---- stage A: x fp32 -> bf16, with SAME-padding zeros ----
        {
            const int hh = hq + kh - 1;
            const int wp = wq + kw - 1;
            const bool valid = ((unsigned)hh < 56u) && ((unsigned)wp < 56u);
            const float* src = xpix + ((kh - 1) * 56 + (kw - 1)) * CI + c0 + halfsel * 16;
            floatx4 f[4];
            if (valid) {
                const floatx4* s4 = (const floatx4*)src;
                f[0] = s4[0]; f[1] = s4[1]; f[2] = s4[2]; f[3] = s4[3];
            } else {
                f[0] = fzero; f[1] = fzero; f[2] = fzero; f[3] = fzero;
            }
            unsigned short* ad = &As[m_local * LDPAD + halfsel * 16];
            #pragma unroll
            for (int j = 0; j < 4; ++j) {
                ushortx4 g;
                #pragma unroll
                for (int e = 0; e < 4; ++e) g[e] = bf16_rne(f[j][e]);
                *(ushortx4*)(ad + j * 4) = g;
            }
        }

        // ---- stage B: pre-transposed bf16 weights, straight copy ----
        #pragma unroll
        for (int it = 0; it < 2; ++it) {
            const int c    = tid + it * 256;   // 0..511 chunks of 8 elems
            const int nrow = c >> 2;
            const int q    = c & 3;
            ushortx8 v = *(const ushortx8*)(wt + (size_t)(bx * BN + nrow) * K_DIM + kk + q * 8);
            *(ushortx8*)&Bs[nrow * LDPAD + q * 8] = v;
        }

        __syncthreads();

        ushortx8 ar[4], br[4];
        #pragma unroll
        for (int mi = 0; mi < 4; ++mi)
            ar[mi] = *(const ushortx8*)&As[(wm + mi * 16 + lrow) * LDPAD + quad * 8];
        #pragma unroll
        for (int ni = 0; ni < 4; ++ni)
            br[ni] = *(const ushortx8*)&Bs[(wn + ni * 16 + lrow) * LDPAD + quad * 8];
        #pragma unroll
        for (int mi = 0; mi < 4; ++mi)
            #pragma unroll
            for (int ni = 0; ni < 4; ++ni)
                acc[mi][ni] = __builtin_amdgcn_mfma_f32_16x16x32_bf16(
                    __builtin_bit_cast(bf16x8, ar[mi]),
                    __builtin_bit_cast(bf16x8, br[ni]),
                    acc[mi][ni], 0, 0, 0);

        __syncthreads();
    }

    // ---- epilogue: bias + store (C/D layout: col=lane&15, row=quad*4+r) ----
    float bv[4];
    #pragma unroll
    for (int ni = 0; ni < 4; ++ni)
        bv[ni] = bias[bx * BN + wn + ni * 16 + lrow];

    #pragma unroll
    for (int mi = 0; mi < 4; ++mi) {
        #pragma unroll
        for (int r = 0; r < 4; ++r) {
            const int row = by * BM + wm + mi * 16 + quad * 4 + r;
            float* o = out + (size_t)row * CO + bx * BN + wn + lrow;
            #pragma unroll
            for (int ni = 0; ni < 4; ++ni)
                o[ni * 16] = acc[mi][ni][r] + bv[ni];
        }
    }
}

extern "C" void kernel_launch(void* const* d_in, const int* in_sizes, int n_in,
                              void* d_out, int out_size, void* d_ws, size_t ws_size,
                              hipStream_t stream) {
    (void)in_sizes; (void)n_in; (void)out_size; (void)ws_size;
    const float* x    = (const float*)d_in[0];
    const float* w    = (const float*)d_in[1];
    const float* bias = (const float*)d_in[2];
    float* out = (float*)d_out;
    unsigned short* wt = (unsigned short*)d_ws;   // bf16 [CO][K_DIM], 0.59 MB

    wt_transpose_kernel<<<dim3((K_DIM * CO) / 256), dim3(256), 0, stream>>>(w, wt);
    conv_gemm_kernel<<<dim3(2, M_DIM / BM), dim3(256), 0, stream>>>(x, wt, bias, out);
}

// Round 2
// 217.089 us; speedup vs baseline: 1.2042x; 1.2042x over previous
//
#include <hip/hip_runtime.h>

#define B_ 32
#define CI 128
#define CO 256
#define K_DIM 1152            // 9*128
#define M_DIM 100352          // 32*56*56
#define BM 128
#define BN 128
#define BK 32
#define KTILES 36
#define HPAD 58               // 56 + halo
#define XB_OFF 589824         // byte offset of xb in ws (after wt: 1152*256*2 B)

typedef float          floatx4  __attribute__((ext_vector_type(4)));
typedef unsigned short ushortx8 __attribute__((ext_vector_type(8)));
typedef __bf16         bf16x8   __attribute__((ext_vector_type(8)));

// address-space helpers for global_load_lds
typedef __attribute__((address_space(1))) void gas_void;
typedef __attribute__((address_space(3))) void las_void;
#define GLD16(g, l) __builtin_amdgcn_global_load_lds( \
    (gas_void*)(uintptr_t)(g), (las_void*)(l), 16, 0, 0)

__device__ __forceinline__ unsigned short bf16_rne(float f) {
    unsigned u = __builtin_bit_cast(unsigned, f);
    u += 0x7FFFu + ((u >> 16) & 1u);
    return (unsigned short)(u >> 16);
}

// ---- prepass 1: w[k][n] fp32 -> wt[n][k] bf16, LDS-tiled (coalesced both sides)
__global__ void wt_transpose_kernel(const float* __restrict__ w,
                                    unsigned short* __restrict__ wt) {
    __shared__ unsigned short tile[64][65];
    const int kt = blockIdx.x * 64, nt = blockIdx.y * 64;
    #pragma unroll
    for (int i = 0; i < 16; ++i) {
        int idx = i * 256 + threadIdx.x;
        int kl = idx >> 6, nl = idx & 63;
        tile[kl][nl] = bf16_rne(w[(size_t)(kt + kl) * CO + nt + nl]);
    }
    __syncthreads();
    #pragma unroll
    for (int i = 0; i < 16; ++i) {
        int idx = i * 256 + threadIdx.x;
        int nl = idx >> 6, kl = idx & 63;
        wt[(size_t)(nt + nl) * K_DIM + kt + kl] = tile[kl][nl];
    }
}

// ---- prepass 2: x fp32 NHWC -> xb bf16 [32][58][58][128] with zero halo
__global__ void xpad_kernel(const float* __restrict__ x,
                            unsigned short* __restrict__ xb) {
    const int t   = blockIdx.x * 256 + threadIdx.x;  // 107648*16 threads
    const int pix = t >> 4;
    const int cc  = (t & 15) << 3;                   // 8-channel chunk
    const int b   = pix / (HPAD * HPAD);
    const int rem = pix % (HPAD * HPAD);
    const int hp  = rem / HPAD, wp = rem % HPAD;
    ushortx8 g = {0, 0, 0, 0, 0, 0, 0, 0};
    if (hp >= 1 && hp <= 56 && wp >= 1 && wp <= 56) {
        const float* s = x + ((size_t)((b * 56 + hp - 1) * 56 + (wp - 1))) * CI + cc;
        floatx4 f0 = ((const floatx4*)s)[0];
        floatx4 f1 = ((const floatx4*)s)[1];
        #pragma unroll
        for (int e = 0; e < 4; ++e) { g[e] = bf16_rne(f0[e]); g[e + 4] = bf16_rne(f1[e]); }
    }
    *(ushortx8*)(xb + (size_t)pix * CI + cc) = g;
}

// ---- main: implicit-GEMM conv, global_load_lds staging, swizzled packed LDS
__global__ __launch_bounds__(256, 2)
void conv_gemm_kernel(const unsigned short* __restrict__ xb,
                      const unsigned short* __restrict__ wt,
                      const float* __restrict__ bias,
                      float* __restrict__ out) {
    __shared__ unsigned short As[BM * BK];   // 8 KB, packed rows of 32, chunk-swizzled
    __shared__ unsigned short Bs[BN * BK];   // 8 KB

    const int tid  = threadIdx.x;
    const int bx   = blockIdx.x;             // n tile 0..1
    const int by   = blockIdx.y;             // m tile 0..783
    const int wid  = tid >> 6;
    const int lane = tid & 63;
    const int lrow = lane & 15;
    const int quad = lane >> 4;
    const int wm   = (wid & 1) * 64;
    const int wn   = (wid >> 1) * 64;

    // staging lane mapping: lane l writes LDS slot l (16 B) = seg-row l>>2, pos l&3;
    // it must FETCH global chunk (pos - (row>>1)) & 3  (swizzle)
    const int rseg = lane >> 2;
    const int cglb = ((lane & 3) - (rseg >> 1)) & 3;

    // A: this lane's two m-rows (instr 0 and 1 of its wave)
    const int ar0 = wid * 32 + rseg;
    const int ar1 = ar0 + 16;
    const int m0 = by * BM + ar0;
    const int m1 = by * BM + ar1;
    const int b0 = m0 / 3136, r0 = m0 % 3136;
    const int b1 = m1 / 3136, r1 = m1 % 3136;
    const unsigned short* ag0 = xb + ((size_t)((b0 * HPAD + r0 / 56) * HPAD + r0 % 56)) * CI + cglb * 8;
    const unsigned short* ag1 = xb + ((size_t)((b1 * HPAD + r1 / 56) * HPAD + r1 % 56)) * CI + cglb * 8;

    // B: this lane's two n-rows
    const unsigned short* bg0 = wt + (size_t)(bx * BN + ar0) * K_DIM + cglb * 8;
    const unsigned short* bg1 = wt + (size_t)(bx * BN + ar1) * K_DIM + cglb * 8;

    // LDS staging bases (wave-uniform: HW writes base + lane*16)
    unsigned short* lA0 = &As[(wid * 32) * BK];
    unsigned short* lA1 = lA0 + 16 * BK;
    unsigned short* lB0 = &Bs[(wid * 32) * BK];
    unsigned short* lB1 = lB0 + 16 * BK;

    // fragment read offsets (row & 15 == lrow for all mi/ni)
    const int swz = ((quad + (lrow >> 1)) & 3) * 8;
    int a_idx[4], b_idx[4];
    #pragma unroll
    for (int i = 0; i < 4; ++i) {
        a_idx[i] = (wm + i * 16 + lrow) * BK + swz;
        b_idx[i] = (wn + i * 16 + lrow) * BK + swz;
    }

    floatx4 acc[4][4] = {};

    for (int kb = 0; kb < KTILES; ++kb) {
        const int p  = kb >> 2;              // patch 0..8
        const int c0 = (kb & 3) << 5;
        const int aoff = (p / 3 * HPAD + p % 3) * CI + c0;   // elems
        const int boff = kb * BK;                             // elems

        GLD16(ag0 + aoff, lA0);
        GLD16(ag1 + aoff, lA1);
        GLD16(bg0 + boff, lB0);
        GLD16(bg1 + boff, lB1);

        __syncthreads();

        ushortx8 arv[4], brv[4];
        #pragma unroll
        for (int mi = 0; mi < 4; ++mi) arv[mi] = *(const ushortx8*)&As[a_idx[mi]];
        #pragma unroll
        for (int ni = 0; ni < 4; ++ni) brv[ni] = *(const ushortx8*)&Bs[b_idx[ni]];
        #pragma unroll
        for (int mi = 0; mi < 4; ++mi)
            #pragma unroll
            for (int ni = 0; ni < 4; ++ni)
                acc[mi][ni] = __builtin_amdgcn_mfma_f32_16x16x32_bf16(
                    __builtin_bit_cast(bf16x8, arv[mi]),
                    __builtin_bit_cast(bf16x8, brv[ni]),
                    acc[mi][ni], 0, 0, 0);

        __syncthreads();
    }

    // epilogue: bias + store (C/D: col=lane&15, row=quad*4+r)
    float bv[4];
    #pragma unroll
    for (int ni = 0; ni < 4; ++ni)
        bv[ni] = bias[bx * BN + wn + ni * 16 + lrow];

    #pragma unroll
    for (int mi = 0; mi < 4; ++mi) {
        #pragma unroll
        for (int r = 0; r < 4; ++r) {
            const int row = by * BM + wm + mi * 16 + quad * 4 + r;
            float* o = out + (size_t)row * CO + bx * BN + wn + lrow;
            #pragma unroll
            for (int ni = 0; ni < 4; ++ni)
                o[ni * 16] = acc[mi][ni][r] + bv[ni];
        }
    }
}

extern "C" void kernel_launch(void* const* d_in, const int* in_sizes, int n_in,
                              void* d_out, int out_size, void* d_ws, size_t ws_size,
                              hipStream_t stream) {
    (void)in_sizes; (void)n_in; (void)out_size; (void)ws_size;
    const float* x    = (const float*)d_in[0];
    const float* w    = (const float*)d_in[1];
    const float* bias = (const float*)d_in[2];
    float* out = (float*)d_out;

    unsigned short* wt = (unsigned short*)d_ws;                     // bf16 [256][1152]
    unsigned short* xb = (unsigned short*)((char*)d_ws + XB_OFF);   // bf16 [32][58][58][128]

    wt_transpose_kernel<<<dim3(K_DIM / 64, CO / 64), dim3(256), 0, stream>>>(w, wt);
    xpad_kernel<<<dim3((B_ * HPAD * HPAD * 16) / 256), dim3(256), 0, stream>>>(x, xb);
    conv_gemm_kernel<<<dim3(2, M_DIM / BM), dim3(256), 0, stream>>>(xb, wt, bias, out);
}

// Round 3
// 215.145 us; speedup vs baseline: 1.2151x; 1.0090x over previous
//
#include <hip/hip_runtime.h>

#define B_ 32
#define CI 128
#define CO 256
#define K_DIM 1152            // 9*128
#define M_DIM 100352          // 32*56*56
#define BM 128
#define BN 128
#define BK 32
#define KTILES 36
#define HPAD 58               // 56 + halo
#define XB_OFF 589824         // byte offset of xb in ws (after wt: 1152*256*2 B)

typedef float          floatx4  __attribute__((ext_vector_type(4)));
typedef unsigned short ushortx8 __attribute__((ext_vector_type(8)));
typedef __bf16         bf16x8   __attribute__((ext_vector_type(8)));

typedef __attribute__((address_space(1))) void gas_void;
typedef __attribute__((address_space(3))) void las_void;
#define GLD16(g, l) __builtin_amdgcn_global_load_lds( \
    (gas_void*)(uintptr_t)(g), (las_void*)(l), 16, 0, 0)

__device__ __forceinline__ unsigned short bf16_rne(float f) {
    unsigned u = __builtin_bit_cast(unsigned, f);
    u += 0x7FFFu + ((u >> 16) & 1u);
    return (unsigned short)(u >> 16);
}

// ---- prepass 1: w[k][n] fp32 -> wt[n][k] bf16, LDS-tiled
__global__ void wt_transpose_kernel(const float* __restrict__ w,
                                    unsigned short* __restrict__ wt) {
    __shared__ unsigned short tile[64][65];
    const int kt = blockIdx.x * 64, nt = blockIdx.y * 64;
    #pragma unroll
    for (int i = 0; i < 16; ++i) {
        int idx = i * 256 + threadIdx.x;
        int kl = idx >> 6, nl = idx & 63;
        tile[kl][nl] = bf16_rne(w[(size_t)(kt + kl) * CO + nt + nl]);
    }
    __syncthreads();
    #pragma unroll
    for (int i = 0; i < 16; ++i) {
        int idx = i * 256 + threadIdx.x;
        int nl = idx >> 6, kl = idx & 63;
        wt[(size_t)(nt + nl) * K_DIM + kt + kl] = tile[kl][nl];
    }
}

// ---- prepass 2: x fp32 NHWC -> xb bf16 [32][58][58][128] with zero halo
__global__ void xpad_kernel(const float* __restrict__ x,
                            unsigned short* __restrict__ xb) {
    const int t   = blockIdx.x * 256 + threadIdx.x;
    const int pix = t >> 4;
    const int cc  = (t & 15) << 3;
    const int b   = pix / (HPAD * HPAD);
    const int rem = pix % (HPAD * HPAD);
    const int hp  = rem / HPAD, wp = rem % HPAD;
    ushortx8 g = {0, 0, 0, 0, 0, 0, 0, 0};
    if (hp >= 1 && hp <= 56 && wp >= 1 && wp <= 56) {
        const float* s = x + ((size_t)((b * 56 + hp - 1) * 56 + (wp - 1))) * CI + cc;
        floatx4 f0 = ((const floatx4*)s)[0];
        floatx4 f1 = ((const floatx4*)s)[1];
        #pragma unroll
        for (int e = 0; e < 4; ++e) { g[e] = bf16_rne(f0[e]); g[e + 4] = bf16_rne(f1[e]); }
    }
    *(ushortx8*)(xb + (size_t)pix * CI + cc) = g;
}

// ---- main: implicit-GEMM conv, dbuf LDS + global_load_lds, 1 barrier/iter
__global__ __launch_bounds__(256, 2)
void conv_gemm_kernel(const unsigned short* __restrict__ xb,
                      const unsigned short* __restrict__ wt,
                      const float* __restrict__ bias,
                      float* __restrict__ out) {
    __shared__ unsigned short As[2][BM * BK];   // 2 x 8 KB, packed, chunk-swizzled
    __shared__ unsigned short Bs[2][BN * BK];   // 2 x 8 KB

    const int tid  = threadIdx.x;
    const int bx   = blockIdx.x;             // n tile 0..1
    const int by   = blockIdx.y;             // m tile 0..783
    const int wid  = tid >> 6;
    const int lane = tid & 63;
    const int lrow = lane & 15;
    const int quad = lane >> 4;
    const int wm   = (wid & 1) * 64;
    const int wn   = (wid >> 1) * 64;

    // staging: lane l -> LDS slot l (16 B) = seg-row l>>2, pos l&3; fetches
    // global chunk (pos - (row>>1)) & 3   (XOR-free swizzle, verified R2)
    const int rseg = lane >> 2;
    const int cglb = ((lane & 3) - (rseg >> 1)) & 3;

    const int ar0 = wid * 32 + rseg;
    const int ar1 = ar0 + 16;
    const int m0 = by * BM + ar0;
    const int m1 = by * BM + ar1;
    const int b0 = m0 / 3136, r0 = m0 % 3136;
    const int b1 = m1 / 3136, r1 = m1 % 3136;
    const unsigned short* ag0 = xb + ((size_t)((b0 * HPAD + r0 / 56) * HPAD + r0 % 56)) * CI + cglb * 8;
    const unsigned short* ag1 = xb + ((size_t)((b1 * HPAD + r1 / 56) * HPAD + r1 % 56)) * CI + cglb * 8;
    const unsigned short* bg0 = wt + (size_t)(bx * BN + ar0) * K_DIM + cglb * 8;
    const unsigned short* bg1 = wt + (size_t)(bx * BN + ar1) * K_DIM + cglb * 8;

    const int ldsA0 = (wid * 32) * BK;      // element offsets within a buffer
    const int ldsA1 = ldsA0 + 16 * BK;

    // fragment read offsets
    const int swz = ((quad + (lrow >> 1)) & 3) * 8;
    int a_idx[4], b_idx[4];
    #pragma unroll
    for (int i = 0; i < 4; ++i) {
        a_idx[i] = (wm + i * 16 + lrow) * BK + swz;
        b_idx[i] = (wn + i * 16 + lrow) * BK + swz;
    }

    floatx4 acc[4][4] = {};

    auto stage = [&](int kb, int buf) {
        const int p    = kb >> 2;                       // patch 0..8
        const int c0   = (kb & 3) << 5;
        const int aoff = (p / 3 * HPAD + p % 3) * CI + c0;
        const int boff = kb * BK;
        GLD16(ag0 + aoff, &As[buf][ldsA0]);
        GLD16(ag1 + aoff, &As[buf][ldsA1]);
        GLD16(bg0 + boff, &Bs[buf][ldsA0]);
        GLD16(bg1 + boff, &Bs[buf][ldsA1]);
    };

    auto compute = [&](int buf) {
        ushortx8 arv[4], brv[4];
        #pragma unroll
        for (int mi = 0; mi < 4; ++mi) arv[mi] = *(const ushortx8*)&As[buf][a_idx[mi]];
        #pragma unroll
        for (int ni = 0; ni < 4; ++ni) brv[ni] = *(const ushortx8*)&Bs[buf][b_idx[ni]];
        #pragma unroll
        for (int mi = 0; mi < 4; ++mi)
            #pragma unroll
            for (int ni = 0; ni < 4; ++ni)
                acc[mi][ni] = __builtin_amdgcn_mfma_f32_16x16x32_bf16(
                    __builtin_bit_cast(bf16x8, arv[mi]),
                    __builtin_bit_cast(bf16x8, brv[ni]),
                    acc[mi][ni], 0, 0, 0);
    };

    stage(0, 0);
    __syncthreads();                        // tile 0 resident
    int cur = 0;
    #pragma unroll 1
    for (int kb = 0; kb < KTILES - 1; ++kb) {
        stage(kb + 1, cur ^ 1);             // prefetch next tile
        compute(cur);                       // overlap flight time with MFMA
        __syncthreads();                    // drain prefetch + protect buf reuse
        cur ^= 1;
    }
    compute(cur);

    // epilogue: bias + store (C/D: col=lane&15, row=quad*4+r)
    float bv[4];
    #pragma unroll
    for (int ni = 0; ni < 4; ++ni)
        bv[ni] = bias[bx * BN + wn + ni * 16 + lrow];

    #pragma unroll
    for (int mi = 0; mi < 4; ++mi) {
        #pragma unroll
        for (int r = 0; r < 4; ++r) {
            const int row = by * BM + wm + mi * 16 + quad * 4 + r;
            float* o = out + (size_t)row * CO + bx * BN + wn + lrow;
            #pragma unroll
            for (int ni = 0; ni < 4; ++ni)
                o[ni * 16] = acc[mi][ni][r] + bv[ni];
        }
    }
}

extern "C" void kernel_launch(void* const* d_in, const int* in_sizes, int n_in,
                              void* d_out, int out_size, void* d_ws, size_t ws_size,
                              hipStream_t stream) {
    (void)in_sizes; (void)n_in; (void)out_size; (void)ws_size;
    const float* x    = (const float*)d_in[0];
    const float* w    = (const float*)d_in[1];
    const float* bias = (const float*)d_in[2];
    float* out = (float*)d_out;

    unsigned short* wt = (unsigned short*)d_ws;                     // bf16 [256][1152]
    unsigned short* xb = (unsigned short*)((char*)d_ws + XB_OFF);   // bf16 [32][58][58][128]

    wt_transpose_kernel<<<dim3(K_DIM / 64, CO / 64), dim3(256), 0, stream>>>(w, wt);
    xpad_kernel<<<dim3((B_ * HPAD * HPAD * 16) / 256), dim3(256), 0, stream>>>(x, xb);
    conv_gemm_kernel<<<dim3(2, M_DIM / BM), dim3(256), 0, stream>>>(xb, wt, bias, out);
}